// Round 6
// baseline (9045.582 us; speedup 1.0000x reference)
//
#include <hip/hip_runtime.h>
#include <stdint.h>

#define B_   64
#define N_   256
#define S_   2000
#define K_   100
#define BIL_ 4
#define NITER_ 200
#define JITTER_ 1e-4f
#define SAFETY_ 0.5f
#define PART_ 8
#define SCH_  (S_ / PART_)   // 250 scenarios per block

// ---- ws layout (offsets in float units) ----
// fp32 Lc (chol output) aliases the epsrm16 region: chol -> lpack read it before
// etrans overwrites (kernels serialize on the stream).
#define OFF_LC16  ((size_t)0)                                   // bf16 L col-major
#define OFF_LR16  (OFF_LC16 + (size_t)B_ * N_ * N_ / 2)         // bf16 L row-major
#define OFF_EPST  (OFF_LR16 + (size_t)B_ * N_ * N_ / 2)         // bf16 epsT[b][n][s]
#define OFF_EPSRM (OFF_EPST + (size_t)B_ * N_ * S_ / 2)         // bf16 eps[b][s][n] (& temp fp32 Lc)
#define OFF_LOSS  (OFF_EPSRM + (size_t)B_ * S_ * N_ / 2)        // uint loss bits, double-buffered
#define OFF_BAR   (OFF_LOSS + (size_t)2 * B_ * S_)              // int barrier counters
// total ~148.9 MB (< round-1's proven 164.6 MB)

// ---------------- helpers ----------------
__device__ __forceinline__ float wred_f(float x) {
#pragma unroll
  for (int off = 32; off > 0; off >>= 1) x += __shfl_xor(x, off);
  return x;
}
__device__ __forceinline__ int wred_i(int x) {
#pragma unroll
  for (int off = 32; off > 0; off >>= 1) x += __shfl_xor(x, off);
  return x;
}
__device__ __forceinline__ unsigned keyd(float x) {
  unsigned u = __float_as_uint(x);
  unsigned ku = (u & 0x80000000u) ? ~u : (u | 0x80000000u);
  return ~ku;
}
__device__ __forceinline__ uint16_t f2b(float f) {  // RNE fp32->bf16
  uint32_t u = __float_as_uint(f);
  uint32_t r = u + 0x7FFFu + ((u >> 16) & 1u);
  return (uint16_t)(r >> 16);
}
__device__ __forceinline__ float blo(uint32_t u) { return __uint_as_float(u << 16); }
__device__ __forceinline__ float bhi(uint32_t u) { return __uint_as_float(u & 0xFFFF0000u); }

// Michelot exact simplex projection (fixed point == reference sort formula); one wave.
__device__ __forceinline__ float michelot4(const float vp[4], float z) {
  bool act[4] = {true, true, true, true};
  float theta = 0.0f;
  int prev = -1;
  for (int pass = 0; pass < 300; ++pass) {
    float ls = 0.0f; int lc = 0;
#pragma unroll
    for (int j = 0; j < 4; ++j) { if (act[j]) { ls += vp[j]; lc += 1; } }
    ls = wred_f(ls);
    lc = wred_i(lc);
    theta = (ls - z) / (float)lc;
    if (lc == prev) break;
    prev = lc;
#pragma unroll
    for (int j = 0; j < 4; ++j) act[j] = (vp[j] > theta);
  }
  return theta;
}

__device__ __forceinline__ void proj_store(const float y[4], float fl_bil, float mass, float muf,
                                           const float* __restrict__ muB, int ln,
                                           float* w_s, float* c_sh) {
  float vp[4];
#pragma unroll
  for (int j = 0; j < 4; ++j) {
    const int n = 4 * ln + j;
    vp[j] = y[j] - ((n == BIL_) ? fl_bil : 0.0f);
  }
  const float theta = michelot4(vp, mass);
  const float4 m4 = *(const float4*)(muB + 4 * ln);
  const float mm[4] = {m4.x, m4.y, m4.z, m4.w};
  float wj[4];
  float cp = 0.0f;
#pragma unroll
  for (int j = 0; j < 4; ++j) {
    const int n = 4 * ln + j;
    wj[j] = fmaxf(vp[j] - theta, 0.0f) + ((n == BIL_) ? fl_bil : 0.0f);
    cp = fmaf(muf * mm[j], wj[j], cp);
  }
  cp = wred_f(cp);
  if (ln == 0) *c_sh = cp;
  *(float4*)(w_s + 4 * ln) = make_float4(wj[0], wj[1], wj[2], wj[3]);
}

// ---------------- Cholesky v3: one block (512 thr) per batch ----------------
__global__ __launch_bounds__(512) void chol_kernel(const float* __restrict__ sigma,
                                                   float* __restrict__ Lc) {
  const int b = blockIdx.x;
  const int tid = threadIdx.x;
  const int i = tid & 255;   // row owned
  const int half = tid >> 8; // 0/1 k-range split
  const float* Sg = sigma + (size_t)b * N_ * N_;
  float* L = Lc + (size_t)b * N_ * N_;
  __shared__ __align__(16) float slab[248 * 8];   // slab[k*8+jj] = L[k][j0+jj]
  __shared__ __align__(16) float spart[256][8];   // upper-half partial sums
  __shared__ __align__(16) float pnl[64];         // panel 8x8: [r*8+m]=L val (m<r), diag=1/d

  for (int j0 = 0; j0 < N_; j0 += 8) {
    for (int x = tid; x < j0 * 8; x += 512) {
      const int k = x >> 3, jj = x & 7;
      slab[x] = L[(size_t)k * N_ + (j0 + jj)];
    }
    float s[8];
    if (half == 0) {
#pragma unroll
      for (int jj = 0; jj < 8; ++jj) {
        float a = Sg[(size_t)(j0 + jj) * N_ + i];  // sigma symmetric -> coalesced
        if (i == j0 + jj) a += JITTER_;
        s[jj] = a;
      }
    } else {
#pragma unroll
      for (int jj = 0; jj < 8; ++jj) s[jj] = 0.0f;
    }
    __syncthreads();  // A: slab ready

    const int kb = half ? (j0 >> 1) : 0;
    const int ke = half ? j0 : (j0 >> 1);
#pragma unroll 4
    for (int k = kb; k < ke; ++k) {
      const float lk = L[(size_t)k * N_ + i];
      const float4 h0 = *(const float4*)&slab[k * 8];
      const float4 h1 = *(const float4*)&slab[k * 8 + 4];
      s[0] = fmaf(-lk, h0.x, s[0]);
      s[1] = fmaf(-lk, h0.y, s[1]);
      s[2] = fmaf(-lk, h0.z, s[2]);
      s[3] = fmaf(-lk, h0.w, s[3]);
      s[4] = fmaf(-lk, h1.x, s[4]);
      s[5] = fmaf(-lk, h1.y, s[5]);
      s[6] = fmaf(-lk, h1.z, s[6]);
      s[7] = fmaf(-lk, h1.w, s[7]);
    }
    if (half == 1) {
      *(float4*)&spart[i][0] = make_float4(s[0], s[1], s[2], s[3]);
      *(float4*)&spart[i][4] = make_float4(s[4], s[5], s[6], s[7]);
    }
    __syncthreads();  // B: partials ready

    if (half == 0) {
      const float4 p0 = *(const float4*)&spart[i][0];
      const float4 p1 = *(const float4*)&spart[i][4];
      s[0] += p0.x; s[1] += p0.y; s[2] += p0.z; s[3] += p0.w;
      s[4] += p1.x; s[5] += p1.y; s[6] += p1.z; s[7] += p1.w;
      if ((i >> 3) == (j0 >> 3)) {
        const int base = j0 & 63;
        const int r = i & 7;
        float l[8], di[8];
#pragma unroll
        for (int m = 0; m < 8; ++m) {
          const float smv = __shfl(s[m], base + m);
          const float d = sqrtf(smv);
          const float dinv = 1.0f / d;
          di[m] = dinv;
          float lm;
          if (r == m) lm = d;
          else if (r > m) lm = s[m] * dinv;
          else lm = 0.0f;
          l[m] = lm;
#pragma unroll
          for (int mm = m + 1; mm < 8; ++mm) {
            s[mm] = fmaf(-lm, __shfl(lm, base + mm), s[mm]);
          }
        }
#pragma unroll
        for (int m = 0; m < 8; ++m) pnl[r * 8 + m] = (m < r) ? l[m] : ((m == r) ? di[r] : 0.0f);
#pragma unroll
        for (int m = 0; m < 8; ++m) L[(size_t)(j0 + m) * N_ + i] = l[m];
      }
    }
    __syncthreads();  // C: pnl ready

    if (half == 0 && (i >> 3) != (j0 >> 3)) {
      float l[8];
      if (i > j0) {
#pragma unroll
        for (int m = 0; m < 8; ++m) {
          float sm = s[m];
#pragma unroll
          for (int mm = 0; mm < 8; ++mm) {
            if (mm < m) sm = fmaf(-l[mm], pnl[m * 8 + mm], sm);
          }
          l[m] = sm * pnl[m * 8 + m];
        }
      } else {
#pragma unroll
        for (int m = 0; m < 8; ++m) l[m] = 0.0f;
      }
#pragma unroll
      for (int m = 0; m < 8; ++m) L[(size_t)(j0 + m) * N_ + i] = l[m];
    }
    __syncthreads();  // D
  }
}

// ---------------- pack L: Lc fp32 -> Lc16 (bf16) + Lr16 (bf16 transposed) ----------------
__global__ __launch_bounds__(256) void lpack_kernel(const float* __restrict__ Lc,
                                                    uint16_t* __restrict__ Lc16,
                                                    uint16_t* __restrict__ Lr16) {
  const int b = blockIdx.x;
  const float* Lp = Lc + (size_t)b * N_ * N_;
  uint16_t* C16 = Lc16 + (size_t)b * N_ * N_;
  uint16_t* R16 = Lr16 + (size_t)b * N_ * N_;
  __shared__ float tl[32][33];
  const int tx = threadIdx.x & 31;
  const int ty = threadIdx.x >> 5;
  for (int kt = 0; kt < 8; ++kt) {
    for (int it = 0; it < 8; ++it) {
#pragma unroll
      for (int rr = 0; rr < 4; ++rr) {
        const int k = kt * 32 + ty + 8 * rr;
        const int ii = it * 32 + tx;
        const float v = Lp[(size_t)k * N_ + ii];
        tl[ty + 8 * rr][tx] = v;
        C16[(size_t)k * N_ + ii] = f2b(v);
      }
      __syncthreads();
#pragma unroll
      for (int rr = 0; rr < 4; ++rr) {
        const int ii = it * 32 + ty + 8 * rr;
        const int k = kt * 32 + tx;
        R16[(size_t)ii * N_ + k] = f2b(tl[tx][ty + 8 * rr]);
      }
      __syncthreads();
    }
  }
}

// ---------------- eps fp32 -> epsT16 + epsrm16 (bf16); zero bar ----------------
__global__ __launch_bounds__(256) void etrans_kernel(const float* __restrict__ eps,
                                                     uint16_t* __restrict__ epsT16,
                                                     uint16_t* __restrict__ epsrm16,
                                                     int* __restrict__ bar) {
  const int b = blockIdx.x;
  const int s0 = blockIdx.y * 50;
  const int t = threadIdx.x;
  if (blockIdx.x == 0 && blockIdx.y == 0 && t < 64) bar[t] = 0;
  __shared__ float tl[50][257];
  const float* E = eps + ((size_t)b * S_ + s0) * N_;
  for (int p = 0; p < 50; ++p) tl[p][t] = E[(size_t)p * N_ + t];
  __syncthreads();
  uint16_t* RM = epsrm16 + ((size_t)b * S_ + s0) * N_;
  for (int p = 0; p < 50; ++p) RM[(size_t)p * N_ + t] = f2b(tl[p][t]);
  uint16_t* ET = epsT16 + (size_t)b * N_ * S_;
  const int g = t / 50, ss = t % 50;
  if (g < 5) {
    for (int q = 0; q < 52; ++q) {
      const int n = q * 5 + g;
      if (n < N_) ET[(size_t)n * S_ + s0 + ss] = f2b(tl[ss][n]);
    }
  }
}

// ---------------- solver: 8 blocks (1024 thr) per batch, PLAIN launch ----------------
// Grid 512 = exact machine capacity (512 x 16 waves = 256 CU x 32 waves); per-CU:
// 2 x 28.4KB LDS <= 160KB, VGPR <= 64 (launch_bounds 1024,8) -> 2 blocks/CU, all
// resident, so the per-batch spin barrier cannot deadlock. Cooperative launch is
// NOT used: the runtime caps cooperative grids at ~256 blocks (r4/r5 evidence).
__global__ __launch_bounds__(1024, 8) void solve_kernel(
    const float* __restrict__ mu, const int* __restrict__ pcrisis,
    const int* __restrict__ plam, const uint16_t* __restrict__ Lc16,
    const uint16_t* __restrict__ Lr16, const uint16_t* __restrict__ epsT16,
    const uint16_t* __restrict__ epsrm16, unsigned* __restrict__ lossbits,
    int* __restrict__ bar, float* __restrict__ out) {
  const int bx = blockIdx.x;
  const int b = bx & (B_ - 1);
  const int part = bx >> 6;  // 0..7; blocks b+64k all land on XCD b%8 under %8 RR
  const int t = threadIdx.x;
  const int ln = t & 63;
  const int s0 = part * SCH_;

  __shared__ __align__(16) float w_s[N_];
  __shared__ __align__(16) float v_s[N_];
  __shared__ __align__(16) float e_s[N_];
  __shared__ __align__(16) float u_s[N_];
  __shared__ __align__(16) float scratch[8][N_];  // matvec partials AND stage-1 partials
  __shared__ __align__(16) float loss_s[S_];
  __shared__ uint16_t lists[S_];
  __shared__ int whist[2][2][256];  // ping-pong banks x 2 copies
  __shared__ float c_sh;
  __shared__ unsigned pref_sh;
  __shared__ int r_sh;
  __shared__ int lcnt;
  __shared__ float sum_sh;

  const int crisis = pcrisis[0];
  const int lamv = plam[0];
  const float muf = 1.0f + ((lamv > 0) ? (1.0f / fmaxf((float)lamv, 0.1f)) : 0.0f);
  const float fl_bil = SAFETY_ * (float)crisis;
  const float mass = 1.0f - fl_bil;

  const uint16_t* LcB = Lc16 + (size_t)b * N_ * N_;
  const uint16_t* LrB = Lr16 + (size_t)b * N_ * N_;
  const float* muB = mu + (size_t)b * N_;
  const uint16_t* epsTB = epsT16 + (size_t)b * N_ * S_;
  const uint16_t* epsRB = epsrm16 + (size_t)b * S_ * N_;

  // init: zero both histogram banks; w0 = proj(uniform)
  for (int x = t; x < 2 * 2 * 256; x += 1024) ((int*)whist)[x] = 0;
  if (t < 64) {
    float y[4];
#pragma unroll
    for (int j = 0; j < 4; ++j) y[j] = 1.0f / (float)N_;
    proj_store(y, fl_bil, mass, muf, muB, ln, w_s, &c_sh);
  }
  __syncthreads();

  for (int it = 0; it < NITER_; ++it) {
    // ---- v = L^T w : v_k = sum_i Lr[i*N+k] * w[i] ----
    {
      const int oct = t >> 7, kp = t & 127;
      const uint32_t* Lp = (const uint32_t*)(LrB) + kp;
      const int i0 = 32 * oct;
      float a0 = 0.0f, a1 = 0.0f;
#pragma unroll 8
      for (int ii = 0; ii < 32; ++ii) {
        const uint32_t u = Lp[(size_t)(i0 + ii) * (N_ / 2)];
        const float ww = w_s[i0 + ii];
        a0 = fmaf(blo(u), ww, a0);
        a1 = fmaf(bhi(u), ww, a1);
      }
      *(float2*)&scratch[oct][2 * kp] = make_float2(a0, a1);
    }
    __syncthreads();
    if (t < N_) {
      v_s[t] = ((scratch[0][t] + scratch[1][t]) + (scratch[2][t] + scratch[3][t])) +
               ((scratch[4][t] + scratch[5][t]) + (scratch[6][t] + scratch[7][t]));
    }
    __syncthreads();

    // ---- stage 1: partial losses for my 250 scenarios (8 n-octants x 125 pairs) ----
    const float cc = c_sh;
    {
      const int q = t >> 7;     // n-octant (32 n)
      const int idx = t & 127;  // scenario-pair
      if (idx < SCH_ / 2) {
        const uint32_t* col =
            (const uint32_t*)(epsTB + (size_t)(32 * q) * S_) + (s0 / 2 + idx);
        float a0 = 0.0f, a1 = 0.0f;
#pragma unroll 8
        for (int j = 0; j < 32; ++j) {
          const uint32_t u = col[(size_t)j * (S_ / 2)];
          const float vv = v_s[32 * q + j];
          a0 = fmaf(blo(u), vv, a0);
          a1 = fmaf(bhi(u), vv, a1);
        }
        *(float2*)&scratch[q][2 * idx] = make_float2(a0, a1);
      }
    }
    __syncthreads();
    // combine + publish (relaxed agent atomics: per-access coherent, no cache-wide fences)
    unsigned* lgbuf = lossbits + ((it & 1) ? (size_t)B_ * S_ : 0) + (size_t)b * S_;
    if (t < SCH_) {
      const float lv = -(cc + (((scratch[0][t] + scratch[1][t]) + (scratch[2][t] + scratch[3][t])) +
                               ((scratch[4][t] + scratch[5][t]) + (scratch[6][t] + scratch[7][t]))));
      loss_s[s0 + t] = lv;
      __hip_atomic_store(&lgbuf[s0 + t], __float_as_uint(lv), __ATOMIC_RELAXED,
                         __HIP_MEMORY_SCOPE_AGENT);
    }
    __syncthreads();  // drains vmcnt for all waves before barrier entry
    if (t == 0) {
      __hip_atomic_fetch_add(&bar[b], 1, __ATOMIC_RELAXED, __HIP_MEMORY_SCOPE_AGENT);
      const int target = PART_ * (it + 1);
      while (__hip_atomic_load(&bar[b], __ATOMIC_RELAXED, __HIP_MEMORY_SCOPE_AGENT) < target) {
        __builtin_amdgcn_s_sleep(2);
      }
    }
    __syncthreads();
    // gather the other parts' losses
    for (int s = t; s < S_; s += 1024) {
      if ((unsigned)(s - s0) >= (unsigned)SCH_) {
        loss_s[s] = __uint_as_float(
            __hip_atomic_load(&lgbuf[s], __ATOMIC_RELAXED, __HIP_MEMORY_SCOPE_AGENT));
      }
    }
    __syncthreads();

    // ---- top-K threshold: 4-pass radix select, 2-copy histograms ----
    unsigned pref = 0;
    int r = K_;
    for (int pass = 0; pass < 4; ++pass) {
      const int shift = 24 - 8 * pass;
      int(*H)[256] = whist[pass & 1];
      const unsigned msk = (pass == 0) ? 0u : (0xFFFFFFFFu << (shift + 8));
      {
        const int hw = t >> 9;  // block half -> histogram copy
        const unsigned k0 = keyd(loss_s[t]);
        if ((k0 & msk) == pref) atomicAdd(&H[hw][(k0 >> shift) & 255], 1);
        if (t + 1024 < S_) {
          const unsigned k1 = keyd(loss_s[t + 1024]);
          if ((k1 & msk) == pref) atomicAdd(&H[hw][(k1 >> shift) & 255], 1);
        }
      }
      __syncthreads();
      if (t < 64) {  // wave 0: reduce 2 hists + rank scan + digit pick
        const int base = 4 * ln;
        int c0 = H[0][base] + H[1][base];
        int c1 = H[0][base + 1] + H[1][base + 1];
        int c2 = H[0][base + 2] + H[1][base + 2];
        int c3 = H[0][base + 3] + H[1][base + 3];
        const int tot = c0 + c1 + c2 + c3;
        int sc = tot;
#pragma unroll
        for (int off = 1; off < 64; off <<= 1) {
          const int o = __shfl_up(sc, off);
          if (ln >= off) sc += o;
        }
        const int excl = sc - tot;
        const bool has = (excl < r) && (r <= sc);
        const unsigned long long bal = __ballot(has);
        const int lstar = __ffsll(bal) - 1;
        if (ln == lstar) {
          const int rr = r - excl;
          int d, rn;
          if (rr <= c0) { d = 0; rn = rr; }
          else if (rr <= c0 + c1) { d = 1; rn = rr - c0; }
          else if (rr <= c0 + c1 + c2) { d = 2; rn = rr - c0 - c1; }
          else { d = 3; rn = rr - c0 - c1 - c2; }
          pref_sh = pref | ((unsigned)(base + d) << shift);
          r_sh = rn;
        }
      } else {
        // waves 1..15: zero the other bank for the next pass / next iteration
        for (int x = t - 64; x < 2 * 256; x += 960) ((int*)whist[(pass + 1) & 1])[x] = 0;
        if (pass == 3 && t == 64) lcnt = 0;
      }
      __syncthreads();
      pref = pref_sh;
      r = r_sh;
    }
    float thresh;
    {
      const unsigned kd = pref;
      const unsigned ub = (kd & 0x80000000u) ? kd : ((~kd) & 0x7FFFFFFFu);
      thresh = __uint_as_float(ub);
    }

    // ---- compact selected scenarios ----
    for (int s = t; s < S_; s += 1024) {
      if (loss_s[s] >= thresh) {
        const int p = atomicAdd(&lcnt, 1);
        lists[p] = (uint16_t)s;
      }
    }
    __syncthreads();
    const int cnt = lcnt;
    const float weight = 1.0f / (float)((cnt > K_) ? cnt : K_);

    // ---- e = sum of selected eps rows: 8 row-groups x 128 n-pairs ----
    {
      const int rt = t >> 7;   // row-group
      const int np = t & 127;  // n-pair
      float a0 = 0.0f, a1 = 0.0f;
      for (int p = rt; p < cnt; p += 8) {
        const uint32_t u = *((const uint32_t*)(epsRB + (size_t)lists[p] * N_) + np);
        a0 += blo(u);
        a1 += bhi(u);
      }
      *(float2*)&scratch[rt][2 * np] = make_float2(a0, a1);
    }
    __syncthreads();
    if (t < N_) {
      e_s[t] = ((scratch[0][t] + scratch[1][t]) + (scratch[2][t] + scratch[3][t])) +
               ((scratch[4][t] + scratch[5][t]) + (scratch[6][t] + scratch[7][t]));
    }
    __syncthreads();

    // ---- u = L e : u_i = sum_k Lc[k*N+i] e[k] ----
    {
      const int oct = t >> 7, ip = t & 127;
      const uint32_t* Lp = (const uint32_t*)(LcB) + ip;
      const int k0 = 32 * oct;
      float a0 = 0.0f, a1 = 0.0f;
#pragma unroll 8
      for (int kk = 0; kk < 32; ++kk) {
        const uint32_t u = Lp[(size_t)(k0 + kk) * (N_ / 2)];
        const float ee = e_s[k0 + kk];
        a0 = fmaf(blo(u), ee, a0);
        a1 = fmaf(bhi(u), ee, a1);
      }
      *(float2*)&scratch[oct][2 * ip] = make_float2(a0, a1);
    }
    __syncthreads();
    if (t < N_) {
      u_s[t] = (((scratch[0][t] + scratch[1][t]) + (scratch[2][t] + scratch[3][t])) +
                ((scratch[4][t] + scratch[5][t]) + (scratch[6][t] + scratch[7][t]))) * weight;
    }
    __syncthreads();

    // ---- w <- proj(w + lr*(mu_eff + u)) ----
    if (t < 64) {
      const float lr = 0.5f / sqrtf((float)it + 1.0f);
      const float4 w4 = *(const float4*)(w_s + 4 * ln);
      const float4 u4 = *(const float4*)(u_s + 4 * ln);
      const float4 m4 = *(const float4*)(muB + 4 * ln);
      float y[4];
      y[0] = w4.x + lr * (muf * m4.x + u4.x);
      y[1] = w4.y + lr * (muf * m4.y + u4.y);
      y[2] = w4.z + lr * (muf * m4.z + u4.z);
      y[3] = w4.w + lr * (muf * m4.w + u4.w);
      proj_store(y, fl_bil, mass, muf, muB, ln, w_s, &c_sh);
    }
    __syncthreads();
  }

  // ---- output (part 0 only): w / (sum + 1e-8) ----
  if (part == 0) {
    if (t < 64) {
      const float4 w4 = *(const float4*)(w_s + 4 * ln);
      const float ssum = wred_f(w4.x + w4.y + w4.z + w4.w);
      if (ln == 0) sum_sh = ssum;
    }
    __syncthreads();
    if (t < N_) out[(size_t)b * N_ + t] = fmaxf(w_s[t], 0.0f) / (sum_sh + 1e-8f);
  }
}

extern "C" void kernel_launch(void* const* d_in, const int* in_sizes, int n_in,
                              void* d_out, int out_size, void* d_ws, size_t ws_size,
                              hipStream_t stream) {
  const float* mu = (const float*)d_in[0];
  const float* sigma = (const float*)d_in[1];
  const float* eps = (const float*)d_in[2];
  const int* crisis = (const int*)d_in[3];
  const int* lam = (const int*)d_in[4];
  float* out = (float*)d_out;
  float* ws = (float*)d_ws;

  uint16_t* Lc16 = (uint16_t*)(ws + OFF_LC16);
  uint16_t* Lr16 = (uint16_t*)(ws + OFF_LR16);
  uint16_t* epsT16 = (uint16_t*)(ws + OFF_EPST);
  uint16_t* epsrm16 = (uint16_t*)(ws + OFF_EPSRM);
  float* Lc = ws + OFF_EPSRM;  // fp32 L aliases epsrm16 (dead before etrans writes it)
  unsigned* lossbits = (unsigned*)(ws + OFF_LOSS);
  int* bar = (int*)(ws + OFF_BAR);

  chol_kernel<<<dim3(B_), dim3(512), 0, stream>>>(sigma, Lc);
  lpack_kernel<<<dim3(B_), dim3(256), 0, stream>>>(Lc, Lc16, Lr16);
  etrans_kernel<<<dim3(B_, S_ / 50), dim3(256), 0, stream>>>(eps, epsT16, epsrm16, bar);

  // Plain launch: grid == exact residency capacity (see kernel comment).
  solve_kernel<<<dim3(PART_ * B_), dim3(1024), 0, stream>>>(
      mu, crisis, lam, Lc16, Lr16, epsT16, epsrm16, lossbits, bar, out);
}

// Round 7
// 4230.304 us; speedup vs baseline: 2.1383x; 2.1383x over previous
//
#include <hip/hip_runtime.h>
#include <stdint.h>

#define B_   64
#define N_   256
#define S_   2000
#define K_   100
#define BIL_ 4
#define NITER_ 200
#define JITTER_ 1e-4f
#define SAFETY_ 0.5f
#define PART_ 4
#define SCH_  (S_ / PART_)   // 500 scenarios per block

// ---- ws layout (offsets in float units) ----
#define OFF_LC16  ((size_t)0)                                   // bf16 L col-major
#define OFF_LR16  (OFF_LC16 + (size_t)B_ * N_ * N_ / 2)         // bf16 L row-major
#define OFF_EPST  (OFF_LR16 + (size_t)B_ * N_ * N_ / 2)         // bf16 epsT[b][n][s]
#define OFF_EPSRM (OFF_EPST + (size_t)B_ * N_ * S_ / 2)         // bf16 eps[b][s][n] (& temp fp32 Lc)
#define OFF_LOSS  (OFF_EPSRM + (size_t)B_ * S_ * N_ / 2)        // uint loss keys, double-buffered
#define OFF_BAR   (OFF_LOSS + (size_t)2 * B_ * S_)              // int barrier counters

// ---------------- helpers ----------------
__device__ __forceinline__ float wred_f(float x) {
#pragma unroll
  for (int off = 32; off > 0; off >>= 1) x += __shfl_xor(x, off);
  return x;
}
__device__ __forceinline__ int wred_i(int x) {
#pragma unroll
  for (int off = 32; off > 0; off >>= 1) x += __shfl_xor(x, off);
  return x;
}
// monotone key: larger loss -> SMALLER key (top-K largest = K smallest keys)
__device__ __forceinline__ unsigned keyd(float x) {
  unsigned u = __float_as_uint(x);
  unsigned ku = (u & 0x80000000u) ? ~u : (u | 0x80000000u);
  return ~ku;
}
__device__ __forceinline__ uint16_t f2b(float f) {  // RNE fp32->bf16
  uint32_t u = __float_as_uint(f);
  uint32_t r = u + 0x7FFFu + ((u >> 16) & 1u);
  return (uint16_t)(r >> 16);
}
__device__ __forceinline__ float blo(uint32_t u) { return __uint_as_float(u << 16); }
__device__ __forceinline__ float bhi(uint32_t u) { return __uint_as_float(u & 0xFFFF0000u); }

// Michelot exact simplex projection (fixed point == reference sort formula); one wave.
__device__ __forceinline__ float michelot4(const float vp[4], float z) {
  bool act[4] = {true, true, true, true};
  float theta = 0.0f;
  int prev = -1;
  for (int pass = 0; pass < 300; ++pass) {
    float ls = 0.0f; int lc = 0;
#pragma unroll
    for (int j = 0; j < 4; ++j) { if (act[j]) { ls += vp[j]; lc += 1; } }
    ls = wred_f(ls);
    lc = wred_i(lc);
    theta = (ls - z) / (float)lc;
    if (lc == prev) break;
    prev = lc;
#pragma unroll
    for (int j = 0; j < 4; ++j) act[j] = (vp[j] > theta);
  }
  return theta;
}

__device__ __forceinline__ void proj_store(const float y[4], float fl_bil, float mass, float muf,
                                           const float* __restrict__ muB, int ln,
                                           float* w_s, float* c_sh) {
  float vp[4];
#pragma unroll
  for (int j = 0; j < 4; ++j) {
    const int n = 4 * ln + j;
    vp[j] = y[j] - ((n == BIL_) ? fl_bil : 0.0f);
  }
  const float theta = michelot4(vp, mass);
  const float4 m4 = *(const float4*)(muB + 4 * ln);
  const float mm[4] = {m4.x, m4.y, m4.z, m4.w};
  float wj[4];
  float cp = 0.0f;
#pragma unroll
  for (int j = 0; j < 4; ++j) {
    const int n = 4 * ln + j;
    wj[j] = fmaxf(vp[j] - theta, 0.0f) + ((n == BIL_) ? fl_bil : 0.0f);
    cp = fmaf(muf * mm[j], wj[j], cp);
  }
  cp = wred_f(cp);
  if (ln == 0) *c_sh = cp;
  *(float4*)(w_s + 4 * ln) = make_float4(wj[0], wj[1], wj[2], wj[3]);
}

// ---------------- Cholesky v3: one block (512 thr) per batch (proven r3) ----------------
__global__ __launch_bounds__(512) void chol_kernel(const float* __restrict__ sigma,
                                                   float* __restrict__ Lc) {
  const int b = blockIdx.x;
  const int tid = threadIdx.x;
  const int i = tid & 255;
  const int half = tid >> 8;
  const float* Sg = sigma + (size_t)b * N_ * N_;
  float* L = Lc + (size_t)b * N_ * N_;
  __shared__ __align__(16) float slab[248 * 8];
  __shared__ __align__(16) float spart[256][8];
  __shared__ __align__(16) float pnl[64];

  for (int j0 = 0; j0 < N_; j0 += 8) {
    for (int x = tid; x < j0 * 8; x += 512) {
      const int k = x >> 3, jj = x & 7;
      slab[x] = L[(size_t)k * N_ + (j0 + jj)];
    }
    float s[8];
    if (half == 0) {
#pragma unroll
      for (int jj = 0; jj < 8; ++jj) {
        float a = Sg[(size_t)(j0 + jj) * N_ + i];
        if (i == j0 + jj) a += JITTER_;
        s[jj] = a;
      }
    } else {
#pragma unroll
      for (int jj = 0; jj < 8; ++jj) s[jj] = 0.0f;
    }
    __syncthreads();

    const int kb = half ? (j0 >> 1) : 0;
    const int ke = half ? j0 : (j0 >> 1);
#pragma unroll 4
    for (int k = kb; k < ke; ++k) {
      const float lk = L[(size_t)k * N_ + i];
      const float4 h0 = *(const float4*)&slab[k * 8];
      const float4 h1 = *(const float4*)&slab[k * 8 + 4];
      s[0] = fmaf(-lk, h0.x, s[0]);
      s[1] = fmaf(-lk, h0.y, s[1]);
      s[2] = fmaf(-lk, h0.z, s[2]);
      s[3] = fmaf(-lk, h0.w, s[3]);
      s[4] = fmaf(-lk, h1.x, s[4]);
      s[5] = fmaf(-lk, h1.y, s[5]);
      s[6] = fmaf(-lk, h1.z, s[6]);
      s[7] = fmaf(-lk, h1.w, s[7]);
    }
    if (half == 1) {
      *(float4*)&spart[i][0] = make_float4(s[0], s[1], s[2], s[3]);
      *(float4*)&spart[i][4] = make_float4(s[4], s[5], s[6], s[7]);
    }
    __syncthreads();

    if (half == 0) {
      const float4 p0 = *(const float4*)&spart[i][0];
      const float4 p1 = *(const float4*)&spart[i][4];
      s[0] += p0.x; s[1] += p0.y; s[2] += p0.z; s[3] += p0.w;
      s[4] += p1.x; s[5] += p1.y; s[6] += p1.z; s[7] += p1.w;
      if ((i >> 3) == (j0 >> 3)) {
        const int base = j0 & 63;
        const int r = i & 7;
        float l[8], di[8];
#pragma unroll
        for (int m = 0; m < 8; ++m) {
          const float smv = __shfl(s[m], base + m);
          const float d = sqrtf(smv);
          const float dinv = 1.0f / d;
          di[m] = dinv;
          float lm;
          if (r == m) lm = d;
          else if (r > m) lm = s[m] * dinv;
          else lm = 0.0f;
          l[m] = lm;
#pragma unroll
          for (int mm = m + 1; mm < 8; ++mm) {
            s[mm] = fmaf(-lm, __shfl(lm, base + mm), s[mm]);
          }
        }
#pragma unroll
        for (int m = 0; m < 8; ++m) pnl[r * 8 + m] = (m < r) ? l[m] : ((m == r) ? di[r] : 0.0f);
#pragma unroll
        for (int m = 0; m < 8; ++m) L[(size_t)(j0 + m) * N_ + i] = l[m];
      }
    }
    __syncthreads();

    if (half == 0 && (i >> 3) != (j0 >> 3)) {
      float l[8];
      if (i > j0) {
#pragma unroll
        for (int m = 0; m < 8; ++m) {
          float sm = s[m];
#pragma unroll
          for (int mm = 0; mm < 8; ++mm) {
            if (mm < m) sm = fmaf(-l[mm], pnl[m * 8 + mm], sm);
          }
          l[m] = sm * pnl[m * 8 + m];
        }
      } else {
#pragma unroll
        for (int m = 0; m < 8; ++m) l[m] = 0.0f;
      }
#pragma unroll
      for (int m = 0; m < 8; ++m) L[(size_t)(j0 + m) * N_ + i] = l[m];
    }
    __syncthreads();
  }
}

// ---------------- pack L ----------------
__global__ __launch_bounds__(256) void lpack_kernel(const float* __restrict__ Lc,
                                                    uint16_t* __restrict__ Lc16,
                                                    uint16_t* __restrict__ Lr16) {
  const int b = blockIdx.x;
  const float* Lp = Lc + (size_t)b * N_ * N_;
  uint16_t* C16 = Lc16 + (size_t)b * N_ * N_;
  uint16_t* R16 = Lr16 + (size_t)b * N_ * N_;
  __shared__ float tl[32][33];
  const int tx = threadIdx.x & 31;
  const int ty = threadIdx.x >> 5;
  for (int kt = 0; kt < 8; ++kt) {
    for (int it = 0; it < 8; ++it) {
#pragma unroll
      for (int rr = 0; rr < 4; ++rr) {
        const int k = kt * 32 + ty + 8 * rr;
        const int ii = it * 32 + tx;
        const float v = Lp[(size_t)k * N_ + ii];
        tl[ty + 8 * rr][tx] = v;
        C16[(size_t)k * N_ + ii] = f2b(v);
      }
      __syncthreads();
#pragma unroll
      for (int rr = 0; rr < 4; ++rr) {
        const int ii = it * 32 + ty + 8 * rr;
        const int k = kt * 32 + tx;
        R16[(size_t)ii * N_ + k] = f2b(tl[tx][ty + 8 * rr]);
      }
      __syncthreads();
    }
  }
}

// ---------------- eps -> bf16 both layouts; zero bar ----------------
__global__ __launch_bounds__(256) void etrans_kernel(const float* __restrict__ eps,
                                                     uint16_t* __restrict__ epsT16,
                                                     uint16_t* __restrict__ epsrm16,
                                                     int* __restrict__ bar) {
  const int b = blockIdx.x;
  const int s0 = blockIdx.y * 50;
  const int t = threadIdx.x;
  if (blockIdx.x == 0 && blockIdx.y == 0 && t < 64) bar[t] = 0;
  __shared__ float tl[50][257];
  const float* E = eps + ((size_t)b * S_ + s0) * N_;
  for (int p = 0; p < 50; ++p) tl[p][t] = E[(size_t)p * N_ + t];
  __syncthreads();
  uint16_t* RM = epsrm16 + ((size_t)b * S_ + s0) * N_;
  for (int p = 0; p < 50; ++p) RM[(size_t)p * N_ + t] = f2b(tl[p][t]);
  uint16_t* ET = epsT16 + (size_t)b * N_ * S_;
  const int g = t / 50, ss = t % 50;
  if (g < 5) {
    for (int q = 0; q < 52; ++q) {
      const int n = q * 5 + g;
      if (n < N_) ET[(size_t)n * S_ + s0 + ss] = f2b(tl[ss][n]);
    }
  }
}

// ---------------- solver: 4 blocks (1024 thr) per batch, grid 256, plain launch ----------------
// r7: register-resident keys, 1-barrier radix passes (redundant all-wave scan),
// u-reduce fused into projection, zeroing fused into v-reduce. ~12 barriers/iter.
__global__ __launch_bounds__(1024) void solve_kernel(
    const float* __restrict__ mu, const int* __restrict__ pcrisis,
    const int* __restrict__ plam, const uint16_t* __restrict__ Lc16,
    const uint16_t* __restrict__ Lr16, const uint16_t* __restrict__ epsT16,
    const uint16_t* __restrict__ epsrm16, unsigned* __restrict__ lossbits,
    int* __restrict__ bar, float* __restrict__ out) {
  const int bx = blockIdx.x;
  const int b = bx & (B_ - 1);
  const int part = bx >> 6;  // 0..3; blocks b+64k land on XCD b%8 under %8 RR
  const int t = threadIdx.x;
  const int ln = t & 63;
  const int s0 = part * SCH_;

  __shared__ __align__(16) float w_s[N_];
  __shared__ __align__(16) float v_s[N_];
  __shared__ __align__(16) float scratch[8][N_];  // matvec/stage1/e partials (flat-aliased)
  __shared__ __align__(16) uint16_t lists[S_];
  __shared__ __align__(16) int hist[4][256];      // one bank per radix pass
  __shared__ float c_sh;
  __shared__ int lcnt;
  __shared__ float sum_sh;

  const int crisis = pcrisis[0];
  const int lamv = plam[0];
  const float muf = 1.0f + ((lamv > 0) ? (1.0f / fmaxf((float)lamv, 0.1f)) : 0.0f);
  const float fl_bil = SAFETY_ * (float)crisis;
  const float mass = 1.0f - fl_bil;

  const uint16_t* LcB = Lc16 + (size_t)b * N_ * N_;
  const uint16_t* LrB = Lr16 + (size_t)b * N_ * N_;
  const float* muB = mu + (size_t)b * N_;
  const uint16_t* epsTB = epsT16 + (size_t)b * N_ * S_;
  const uint16_t* epsRB = epsrm16 + (size_t)b * S_ * N_;
  float* sc1 = &scratch[0][0];

  // ---- w0 = proj(uniform) ----
  if (t < 64) {
    float y[4];
#pragma unroll
    for (int j = 0; j < 4; ++j) y[j] = 1.0f / (float)N_;
    proj_store(y, fl_bil, mass, muf, muB, ln, w_s, &c_sh);
  }
  __syncthreads();  // B1

  for (int it = 0; it < NITER_; ++it) {
    // ---- v = L^T w partials: 8 i-octants x 128 k-pairs ----
    {
      const int oct = t >> 7, kp = t & 127;
      const uint32_t* Lp = (const uint32_t*)(LrB) + kp;
      const int i0 = 32 * oct;
      float a0 = 0.0f, a1 = 0.0f;
#pragma unroll 8
      for (int ii = 0; ii < 32; ++ii) {
        const uint32_t u = Lp[(size_t)(i0 + ii) * (N_ / 2)];
        const float ww = w_s[i0 + ii];
        a0 = fmaf(blo(u), ww, a0);
        a1 = fmaf(bhi(u), ww, a1);
      }
      *(float2*)&scratch[oct][2 * kp] = make_float2(a0, a1);
    }
    __syncthreads();  // B2

    // ---- v-reduce (t<256) + zero hist banks & lcnt (t>=256) ----
    if (t < N_) {
      v_s[t] = ((scratch[0][t] + scratch[1][t]) + (scratch[2][t] + scratch[3][t])) +
               ((scratch[4][t] + scratch[5][t]) + (scratch[6][t] + scratch[7][t]));
    } else {
      for (int x = t - 256; x < 4 * 256; x += 768) ((int*)hist)[x] = 0;
      if (t == 256) lcnt = 0;
    }
    __syncthreads();  // B3

    // ---- stage 1: partial losses for my 500 scenarios (4 n-quarters x 250 pairs) ----
    const float cc = c_sh;
    {
      const int q = t >> 8;     // n-quarter (64 n)
      const int idx = t & 255;  // scenario-pair
      if (idx < SCH_ / 2) {
        const uint32_t* col = (const uint32_t*)(epsTB + (size_t)(64 * q) * S_) + (s0 / 2 + idx);
        float a0 = 0.0f, a1 = 0.0f;
#pragma unroll 8
        for (int j = 0; j < 64; ++j) {
          const uint32_t u = col[(size_t)j * (S_ / 2)];
          const float vv = v_s[64 * q + j];
          a0 = fmaf(blo(u), vv, a0);
          a1 = fmaf(bhi(u), vv, a1);
        }
        *(float2*)&sc1[q * SCH_ + 2 * idx] = make_float2(a0, a1);
      }
    }
    __syncthreads();  // B4

    // ---- combine + publish keys (relaxed agent atomics) ----
    unsigned* lgbuf = lossbits + ((it & 1) ? (size_t)B_ * S_ : 0) + (size_t)b * S_;
    if (t < SCH_) {
      const float lv = -(cc + ((sc1[t] + sc1[SCH_ + t]) + (sc1[2 * SCH_ + t] + sc1[3 * SCH_ + t])));
      __hip_atomic_store(&lgbuf[s0 + t], keyd(lv), __ATOMIC_RELAXED, __HIP_MEMORY_SCOPE_AGENT);
    }
    __syncthreads();  // B5 (drains vmcnt before barrier exit)

    // ---- per-batch spin barrier ----
    if (t == 0) {
      __hip_atomic_fetch_add(&bar[b], 1, __ATOMIC_RELAXED, __HIP_MEMORY_SCOPE_AGENT);
      const int target = PART_ * (it + 1);
      while (__hip_atomic_load(&bar[b], __ATOMIC_RELAXED, __HIP_MEMORY_SCOPE_AGENT) < target) {
        __builtin_amdgcn_s_sleep(1);
      }
    }
    __syncthreads();  // B6

    // ---- gather all 2000 keys into registers (thread t owns scenarios 2t, 2t+1) + pass-0 hist ----
    uint32_t kx = 0xFFFFFFFFu, ky = 0xFFFFFFFFu;
    if (t < S_ / 2) {
      const unsigned long long two = __hip_atomic_load(
          (const unsigned long long*)(lgbuf + 2 * t), __ATOMIC_RELAXED, __HIP_MEMORY_SCOPE_AGENT);
      kx = (uint32_t)two;
      ky = (uint32_t)(two >> 32);
      atomicAdd(&hist[0][kx >> 24], 1);
      atomicAdd(&hist[0][ky >> 24], 1);
    }
    __syncthreads();  // B7

    // ---- 4-pass radix select: redundant all-wave scan (no publish barrier) ----
    unsigned pref = 0;
    int r = K_;
#pragma unroll
    for (int pass = 0; pass < 4; ++pass) {
      const int shift = 24 - 8 * pass;
      // redundant scan of hist[pass] by every wave
      {
        const int4 c4 = *(const int4*)&hist[pass][4 * ln];
        const int c0 = c4.x, c1 = c4.y, c2 = c4.z, c3 = c4.w;
        const int tot = c0 + c1 + c2 + c3;
        int sc = tot;
#pragma unroll
        for (int off = 1; off < 64; off <<= 1) {
          const int o = __shfl_up(sc, off);
          if (ln >= off) sc += o;
        }
        const int excl = sc - tot;
        const bool has = (excl < r) && (r <= sc);
        const unsigned long long bal = __ballot(has);
        const int lstar = __ffsll(bal) - 1;
        const int bc0 = __shfl(c0, lstar);
        const int bc1 = __shfl(c1, lstar);
        const int bc2 = __shfl(c2, lstar);
        const int bexcl = __shfl(excl, lstar);
        const int rr = r - bexcl;
        int d, rn;
        if (rr <= bc0) { d = 0; rn = rr; }
        else if (rr <= bc0 + bc1) { d = 1; rn = rr - bc0; }
        else if (rr <= bc0 + bc1 + bc2) { d = 2; rn = rr - bc0 - bc1; }
        else { d = 3; rn = rr - bc0 - bc1 - bc2; }
        pref |= (unsigned)(4 * lstar + d) << shift;
        r = rn;
      }
      if (pass < 3) {
        // next-pass histogram over prefix-matching keys (registers)
        const unsigned msk = 0xFFFFFFFFu << shift;
        const int nshift = shift - 8;
        if (t < S_ / 2) {
          if ((kx & msk) == pref) atomicAdd(&hist[pass + 1][(kx >> nshift) & 255], 1);
          if ((ky & msk) == pref) atomicAdd(&hist[pass + 1][(ky >> nshift) & 255], 1);
        }
      } else {
        // compact: selected = key <= pref (== loss >= K-th largest loss)
        if (t < S_ / 2) {
          if (kx <= pref) { const int p = atomicAdd(&lcnt, 1); lists[p] = (uint16_t)(2 * t); }
          if (ky <= pref) { const int p = atomicAdd(&lcnt, 1); lists[p] = (uint16_t)(2 * t + 1); }
        }
      }
      __syncthreads();  // B8..B11
    }

    const int cnt = lcnt;
    const float weight = 1.0f / (float)((cnt > K_) ? cnt : K_);

    // ---- e partials: 8 row-groups x 128 n-pairs ----
    {
      const int rt = t >> 7;
      const int np = t & 127;
      float a0 = 0.0f, a1 = 0.0f;
      for (int p = rt; p < cnt; p += 8) {
        const uint32_t u = *((const uint32_t*)(epsRB + (size_t)lists[p] * N_) + np);
        a0 += blo(u);
        a1 += bhi(u);
      }
      *(float2*)&scratch[rt][2 * np] = make_float2(a0, a1);
    }
    __syncthreads();  // B12

    // ---- projection with fused u-reduce (wave 0): w <- proj(w + lr*(mu_eff + L e * weight)) ----
    if (t < 64) {
      float4 acc = make_float4(0.0f, 0.0f, 0.0f, 0.0f);
#pragma unroll
      for (int oct = 0; oct < 8; ++oct) {
        const float4 x = *(const float4*)&scratch[oct][4 * ln];
        acc.x += x.x; acc.y += x.y; acc.z += x.z; acc.w += x.w;
      }
      // NOTE: e here is Sigma_p eps_p summed over ROWS; u_i = sum_k Lc[k][i] e_k requires the
      // L-matvec. acc currently holds e-partials only for columns 4ln..4ln+3; we still need
      // u = L e. Do it with the full block below instead.
      *(float4*)&v_s[4 * ln] = acc;  // stash e (v_s free until next iter's stage-1... NOT - see below)
    }
    __syncthreads();  // B12b: e ready in v_s

    // ---- u = L e partials: 8 k-octants x 128 i-pairs ----
    {
      const int oct = t >> 7, ip = t & 127;
      const uint32_t* Lp = (const uint32_t*)(LcB) + ip;
      const int k0 = 32 * oct;
      float a0 = 0.0f, a1 = 0.0f;
#pragma unroll 8
      for (int kk = 0; kk < 32; ++kk) {
        const uint32_t u = Lp[(size_t)(k0 + kk) * (N_ / 2)];
        const float ee = v_s[k0 + kk];
        a0 = fmaf(blo(u), ee, a0);
        a1 = fmaf(bhi(u), ee, a1);
      }
      *(float2*)&scratch[oct][2 * ip] = make_float2(a0, a1);
    }
    __syncthreads();  // B13

    // ---- w update + projection (wave 0), u-reduce fused ----
    if (t < 64) {
      float4 u4 = make_float4(0.0f, 0.0f, 0.0f, 0.0f);
#pragma unroll
      for (int oct = 0; oct < 8; ++oct) {
        const float4 x = *(const float4*)&scratch[oct][4 * ln];
        u4.x += x.x; u4.y += x.y; u4.z += x.z; u4.w += x.w;
      }
      const float lr = 0.5f / sqrtf((float)it + 1.0f);
      const float4 w4 = *(const float4*)(w_s + 4 * ln);
      const float4 m4 = *(const float4*)(muB + 4 * ln);
      float y[4];
      y[0] = w4.x + lr * (muf * m4.x + u4.x * weight);
      y[1] = w4.y + lr * (muf * m4.y + u4.y * weight);
      y[2] = w4.z + lr * (muf * m4.z + u4.z * weight);
      y[3] = w4.w + lr * (muf * m4.w + u4.w * weight);
      proj_store(y, fl_bil, mass, muf, muB, ln, w_s, &c_sh);
    }
    __syncthreads();  // B14 (doubles as next iteration's B1)
  }

  // ---- output (part 0 only): w / (sum + 1e-8) ----
  if (part == 0) {
    if (t < 64) {
      const float4 w4 = *(const float4*)(w_s + 4 * ln);
      const float ssum = wred_f(w4.x + w4.y + w4.z + w4.w);
      if (ln == 0) sum_sh = ssum;
    }
    __syncthreads();
    if (t < N_) out[(size_t)b * N_ + t] = fmaxf(w_s[t], 0.0f) / (sum_sh + 1e-8f);
  }
}

extern "C" void kernel_launch(void* const* d_in, const int* in_sizes, int n_in,
                              void* d_out, int out_size, void* d_ws, size_t ws_size,
                              hipStream_t stream) {
  const float* mu = (const float*)d_in[0];
  const float* sigma = (const float*)d_in[1];
  const float* eps = (const float*)d_in[2];
  const int* crisis = (const int*)d_in[3];
  const int* lam = (const int*)d_in[4];
  float* out = (float*)d_out;
  float* ws = (float*)d_ws;

  uint16_t* Lc16 = (uint16_t*)(ws + OFF_LC16);
  uint16_t* Lr16 = (uint16_t*)(ws + OFF_LR16);
  uint16_t* epsT16 = (uint16_t*)(ws + OFF_EPST);
  uint16_t* epsrm16 = (uint16_t*)(ws + OFF_EPSRM);
  float* Lc = ws + OFF_EPSRM;  // fp32 L aliases epsrm16 (dead before etrans writes it)
  unsigned* lossbits = (unsigned*)(ws + OFF_LOSS);
  int* bar = (int*)(ws + OFF_BAR);

  chol_kernel<<<dim3(B_), dim3(512), 0, stream>>>(sigma, Lc);
  lpack_kernel<<<dim3(B_), dim3(256), 0, stream>>>(Lc, Lc16, Lr16);
  etrans_kernel<<<dim3(B_, S_ / 50), dim3(256), 0, stream>>>(eps, epsT16, epsrm16, bar);

  solve_kernel<<<dim3(PART_ * B_), dim3(1024), 0, stream>>>(
      mu, crisis, lam, Lc16, Lr16, epsT16, epsrm16, lossbits, bar, out);
}